// Round 4
// baseline (96.329 us; speedup 1.0000x reference)
//
#include <hip/hip_runtime.h>
#include <hip/hip_bf16.h>
#include <stdint.h>

typedef __attribute__((ext_vector_type(8))) short bf16x8;
typedef __attribute__((ext_vector_type(4))) float f32x4;

#define TWO_N 8192
#define NHALF 4096
#define DIM   128

// sqrt(2 / (tau * ln2)) with tau = 0.5 : rows pre-scaled so dot = logit/ln2
#define SQRT_C 1.69864361f
#define LN2    0.69314718055994531f

// RNE f32 -> bf16 bits (inputs finite)
__device__ __forceinline__ unsigned int f2bf(float f) {
  unsigned int u = __float_as_uint(f);
  u += 0x7FFFu + ((u >> 16) & 1u);
  return u >> 16;
}

// ---------------- Kernel A: normalize+prescale rows of [zjs; zis] -> bf16 ----------------
__global__ __launch_bounds__(256) void norm_kernel(
    const float* __restrict__ zis, const float* __restrict__ zjs,
    unsigned int* __restrict__ rbf /* packed 2x bf16 per uint */) {
  const int wave = threadIdx.x >> 6;
  const int lane = threadIdx.x & 63;
  const int row = blockIdx.x * 4 + wave;
  const float* src = (row < NHALF) ? (zjs + (size_t)row * DIM)
                                   : (zis + (size_t)(row - NHALF) * DIM);
  float2 v = ((const float2*)src)[lane];
  float ss = v.x * v.x + v.y * v.y;
#pragma unroll
  for (int m = 1; m <= 32; m <<= 1) ss += __shfl_xor(ss, m);
  const float scale = SQRT_C / fmaxf(sqrtf(ss), 1e-8f);
  const unsigned int lo = f2bf(v.x * scale);
  const unsigned int hi = f2bf(v.y * scale);
  rbf[(size_t)row * (DIM / 2) + lane] = lo | (hi << 16);
}

// async 16B global->LDS; LDS dest is wave-uniform-base + lane*16 (linear order)
#define GLL16(SRC, DST) __builtin_amdgcn_global_load_lds( \
    (__attribute__((address_space(1))) void*)(SRC),       \
    (__attribute__((address_space(3))) void*)(DST), 16, 0, 0)

// stage a 128-row x 256B panel (XOR-swizzle applied via pre-swizzled source addr:
// LDS[row][cb] = global[row][cb ^ swz]; readers apply the same XOR -> rule #21 ok)
#define STAGE128(ROWBASE, DST) do {                                        \
  _Pragma("unroll")                                                        \
  for (int i_ = 0; i_ < 8; ++i_) {                                         \
    const int L_ = (i_ * 256 + t) * 16;                                    \
    const int row_ = L_ >> 8;                                              \
    const int cb_ = L_ & 255;                                              \
    GLL16(rbytes + (size_t)((ROWBASE) + row_) * 256 +                      \
              (cb_ ^ ((row_ & 7) << 4)),                                   \
          (DST) + L_);                                                     \
  }                                                                        \
} while (0)

// hoist A fragments (64x128 per wave-row pair) from an LDS panel into a_reg
#define HOIST_A(SRCBUF) do {                                               \
  _Pragma("unroll")                                                        \
  for (int ks_ = 0; ks_ < 4; ++ks_)                                        \
    _Pragma("unroll")                                                      \
    for (int m_ = 0; m_ < 4; ++m_) {                                       \
      const int row_ = wr * 64 + m_ * 16 + lcol;                           \
      const int kb_ = ks_ * 64 + lrow * 16;                                \
      a_reg[ks_][m_] = *(const bf16x8*)((SRCBUF) + row_ * 256 +            \
                                        (kb_ ^ ((row_ & 7) << 4)));        \
    }                                                                      \
} while (0)

// ---------------- Kernel B: upper-triangle fused sim-tile GEMM + sum-of-exp ----------------
// 2080 upper tiles (i<=j) of 128x128 over the 64x64 tile grid, distributed
// 4-5 per block across 512 blocks (2 blocks/CU). Row-sums -> slot 2j+wc,
// col-sums -> slot 2i+wr of s_part[128][8192]; every entry written once.
__global__ __launch_bounds__(256)
__attribute__((amdgpu_waves_per_eu(2, 2)))
void simloss_kernel(
    char* __restrict__ rbytes,        // bf16 r matrix, row-major [8192][256B]
    float* __restrict__ pos,          // [8192] v = logit/ln2 for partner
    float* __restrict__ s_part) {     // [128][8192] partial sum-of-exp
  __shared__ char Buf0[32768];
  __shared__ char Buf1[32768];
  const int t = threadIdx.x;
  const int b = blockIdx.x;
  const int Tstart = (65 * b) >> 4;
  const int Tend = (65 * (b + 1)) >> 4;
  const int wave = t >> 6;
  const int lane = t & 63;
  const int wr = wave >> 1, wc = wave & 1;
  const int lrow = lane >> 4, lcol = lane & 15;

  // map Tstart -> (i, j) in the row-major upper triangle (only place needing sqrt)
  int ci = (int)((129.0f - sqrtf((float)(16641 - 8 * Tstart))) * 0.5f);
  if (ci > 63) ci = 63;
  while ((ci + 1) * (129 - (ci + 1)) / 2 <= Tstart) ++ci;
  while (ci * (129 - ci) / 2 > Tstart) --ci;
  int cj = ci + (Tstart - ci * (129 - ci) / 2);

  STAGE128(ci * 128, Buf0);   // A panel
  STAGE128(cj * 128, Buf1);   // B panel for first tile
  __syncthreads();            // vmcnt(0) drain

  bf16x8 a_reg[4][4];
  HOIST_A(Buf0);
  __syncthreads();            // all waves done reading Buf0 before reuse

  char* curB = Buf1;
  char* nxtB = Buf0;

#pragma unroll 1
  for (int q = Tstart; q < Tend; ++q) {
    const int i = ci, j = cj;
    const bool more = (q + 1 < Tend);
    // successor tile in T-order: (i, j+1) or (i+1, i+1)
    const bool sw = (j == 63);              // next tile switches A panel
    const int in1 = sw ? i + 1 : i;
    const int jn1 = sw ? i + 1 : j + 1;
    if (more) {
      if (!sw) STAGE128(jn1 * 128, nxtB);   // prefetch next B panel
      else     STAGE128(in1 * 128, nxtB);   // prefetch next A panel
    }

    f32x4 acc[4][4];
#pragma unroll
    for (int m = 0; m < 4; ++m)
#pragma unroll
      for (int n = 0; n < 4; ++n) acc[m][n] = (f32x4){0.f, 0.f, 0.f, 0.f};

#pragma unroll
    for (int ks = 0; ks < 4; ++ks) {
      bf16x8 bfr[4];
#pragma unroll
      for (int n = 0; n < 4; ++n) {
        const int row = wc * 64 + n * 16 + lcol;
        const int kb = ks * 64 + lrow * 16;
        bfr[n] = *(const bf16x8*)(curB + row * 256 + (kb ^ ((row & 7) << 4)));
      }
#pragma unroll
      for (int m = 0; m < 4; ++m)
#pragma unroll
        for (int n = 0; n < 4; ++n)
          acc[m][n] = __builtin_amdgcn_mfma_f32_16x16x32_bf16(
              a_reg[ks][m], bfr[n], acc[m][n], 0, 0, 0);
    }

    // epilogue: e = exp2(v); accumulate row partials [m][r] and col partials [n]
    const bool diag_tile = (i == j);
    const bool partner_tile = (j == i + 32);
    float rsum[4][4];
    float csum[4];
#pragma unroll
    for (int m = 0; m < 4; ++m)
#pragma unroll
      for (int r = 0; r < 4; ++r) rsum[m][r] = 0.0f;
#pragma unroll
    for (int n = 0; n < 4; ++n) csum[n] = 0.0f;

#pragma unroll
    for (int m = 0; m < 4; ++m) {
#pragma unroll
      for (int n = 0; n < 4; ++n) {
        const bool onsub = (wc == wr) && (n == m);   // sub-block on tile diagonal band
#pragma unroll
        for (int r = 0; r < 4; ++r) {
          const float v = acc[m][n][r];
          float e = __builtin_amdgcn_exp2f(v);
          const bool mine = onsub && (lcol == lrow * 4 + r);
          if (partner_tile && mine) {
            const int row = i * 128 + wr * 64 + m * 16 + lrow * 4 + r;
            pos[row] = v;
            pos[row + 4096] = v;   // sim symmetric: same value serves partner row
          }
          if (diag_tile && mine) e = 0.0f;  // exclude j==i element
          rsum[m][r] += e;
          csum[n] += e;
        }
      }
    }

    // flush row-sums: butterfly over the 16 lcol lanes -> slot 2j+wc
#pragma unroll
    for (int m = 0; m < 4; ++m)
#pragma unroll
      for (int r = 0; r < 4; ++r) {
        float s = rsum[m][r];
        s += __shfl_xor(s, 1);
        s += __shfl_xor(s, 2);
        s += __shfl_xor(s, 4);
        s += __shfl_xor(s, 8);
        if (lcol == 0)
          s_part[(size_t)(2 * j + wc) * TWO_N +
                 (i * 128 + wr * 64 + m * 16 + lrow * 4 + r)] = s;
      }

    // flush col-sums (skip on diagonal tiles: rows already cover the full tile)
    if (!diag_tile) {
#pragma unroll
      for (int n = 0; n < 4; ++n) {
        float c = csum[n];
        c += __shfl_xor(c, 16);
        c += __shfl_xor(c, 32);
        if (lrow == 0)
          s_part[(size_t)(2 * i + wr) * TWO_N +
                 (j * 128 + wc * 64 + n * 16 + lcol)] = c;
      }
    }

    __syncthreads();  // prefetch landed (vmcnt drain) AND all waves done with curB

    if (more) {
      if (!sw) {
        char* tmp = curB; curB = nxtB; nxtB = tmp;
      } else {
        HOIST_A(nxtB);                       // new A panel -> regs
        STAGE128(jn1 * 128, curB);           // B for next tile into freed buffer
        __syncthreads();                     // drain (also orders hoist vs later overwrite)
      }
      ci = in1; cj = jn1;
    }
  }
}

// ---------------- Kernel C1: per-row loss, 32-block partial sums ----------------
__global__ __launch_bounds__(256) void reduce1_kernel(
    const float* __restrict__ pos, const float* __restrict__ s_part,
    float* __restrict__ partial) {
  const int t = threadIdx.x;
  const int row = blockIdx.x * 256 + t;
  float s = 0.0f;
#pragma unroll 8
  for (int q = 0; q < 128; ++q) s += s_part[(size_t)q * TWO_N + row];
  // loss_row = ln(denom) - 2*sim_pos = ln2 * (log2(denom) - v_pos)
  float local = (__log2f(s) - pos[row]) * LN2;
#pragma unroll
  for (int m = 1; m <= 32; m <<= 1) local += __shfl_xor(local, m);
  __shared__ float wsum[4];
  if ((t & 63) == 0) wsum[t >> 6] = local;
  __syncthreads();
  if (t == 0) partial[blockIdx.x] = wsum[0] + wsum[1] + wsum[2] + wsum[3];
}

// ---------------- Kernel C2: combine 32 partials -> scalar ----------------
__global__ __launch_bounds__(64) void reduce2_kernel(
    const float* __restrict__ partial, float* __restrict__ out) {
  float v = (threadIdx.x < 32) ? partial[threadIdx.x] : 0.0f;
#pragma unroll
  for (int m = 1; m <= 32; m <<= 1) v += __shfl_xor(v, m);
  if (threadIdx.x == 0) out[0] = v * (1.0f / TWO_N);
}

extern "C" void kernel_launch(void* const* d_in, const int* in_sizes, int n_in,
                              void* d_out, int out_size, void* d_ws, size_t ws_size,
                              hipStream_t stream) {
  const float* zis = (const float*)d_in[0];
  const float* zjs = (const float*)d_in[1];
  char* ws = (char*)d_ws;
  unsigned int* rbf = (unsigned int*)ws;                          // 2 MB: bf16 r
  float* pos = (float*)(ws + 2u * 1024 * 1024);                   // 32 KB
  float* s_part = (float*)(ws + 2u * 1024 * 1024 + 32 * 1024);    // 4 MB
  float* partial = (float*)(ws + 6u * 1024 * 1024 + 32 * 1024);   // 128 B

  norm_kernel<<<TWO_N / 4, 256, 0, stream>>>(zis, zjs, rbf);
  simloss_kernel<<<512, 256, 0, stream>>>((char*)rbf, pos, s_part);
  reduce1_kernel<<<TWO_N / 256, 256, 0, stream>>>(pos, s_part, partial);
  reduce2_kernel<<<1, 64, 0, stream>>>(partial, (float*)d_out);
}